// Round 9
// baseline (252.898 us; speedup 1.0000x reference)
//
#include <hip/hip_runtime.h>
#include <cstdint>

#define B_SZ   16384
#define H_SZ   512
#define DIN    256
#define TEMB   16
#define KP     1344          // packed K: x[0,256) h[256,768) c[768,1280) delt[1280,1296) pad[1296,1344)
#define KPB    2688          // KP*2 bytes per row
#define BH     8388608L      // B_SZ*H_SZ
#define SLOT   49152         // LDS slot: A 8 KB (128 rows x 64 B) + W 5 regions x 8 KB
#define GSTR   1376256       // 512*KPB: gate stride in Wp bytes

typedef __attribute__((ext_vector_type(4))) float f32x4;
typedef __bf16 bf16x8 __attribute__((ext_vector_type(8)));

typedef const __attribute__((address_space(1))) unsigned int gu32_t;
typedef __attribute__((address_space(3)))       unsigned int lu32_t;

// gate -> W region (t and tt share region 4: never co-active)
__device__ constexpr int RG[6] = {0, 1, 4, 3, 2, 4};

__device__ __forceinline__ void gld16(const void* g, void* l) {
  __builtin_amdgcn_global_load_lds((gu32_t*)(uintptr_t)g,
                                   (lu32_t*)(unsigned int)(uintptr_t)l, 16, 0, 0);
}

__device__ __forceinline__ unsigned short f2bf(float f) {
  unsigned int u = __float_as_uint(f);
  u += 0x7FFFu + ((u >> 16) & 1u);   // RNE; inputs finite
  return (unsigned short)(u >> 16);
}

__device__ __forceinline__ float sigm(float v)  { return 1.0f / (1.0f + __expf(-v)); }
__device__ __forceinline__ float tanhx(float v) { return 2.0f / (1.0f + __expf(-2.0f * v)) - 1.0f; }

// ---------------- prep: pack A = [x|h|c|delt|0] as bf16 [B][KP] ----------------
__global__ void prep_a_kernel(const float* __restrict__ x, const float* __restrict__ h,
                              const float* __restrict__ c, const float* __restrict__ dl,
                              unsigned short* __restrict__ Ap) {
  long idx = (long)blockIdx.x * 256 + threadIdx.x;
  const long n4 = (long)B_SZ * KP / 4;
  if (idx >= n4) return;
  int row = (int)(idx / (KP / 4));
  int k4  = (int)(idx % (KP / 4)) * 4;
  float4 v = make_float4(0.f, 0.f, 0.f, 0.f);
  if (k4 < 256)       v = *(const float4*)(x  + (long)row * DIN  + k4);
  else if (k4 < 768)  v = *(const float4*)(h  + (long)row * H_SZ + (k4 - 256));
  else if (k4 < 1280) v = *(const float4*)(c  + (long)row * H_SZ + (k4 - 768));
  else if (k4 < 1296) v = *(const float4*)(dl + (long)row * TEMB + (k4 - 1280));
  ushort4 o;
  o.x = f2bf(v.x); o.y = f2bf(v.y); o.z = f2bf(v.z); o.w = f2bf(v.w);
  *(ushort4*)(Ap + idx * 4) = o;
}

// ---------------- prep: pack Wp[6][512][KP] bf16 ----------------
__global__ void prep_w_kernel(const float* __restrict__ Wix, const float* __restrict__ Wih, const float* __restrict__ Wic,
                              const float* __restrict__ Wfx, const float* __restrict__ Wfh, const float* __restrict__ Wfc,
                              const float* __restrict__ Wtx, const float* __restrict__ Wtt,
                              const float* __restrict__ Wcx, const float* __restrict__ Wch,
                              const float* __restrict__ Wox, const float* __restrict__ Woh,
                              const float* __restrict__ Woc, const float* __restrict__ Wot,
                              unsigned short* __restrict__ Wp) {
  long idx = (long)blockIdx.x * 256 + threadIdx.x;
  const long n4 = 6L * H_SZ * KP / 4;
  if (idx >= n4) return;
  int k4   = (int)(idx % (KP / 4)) * 4;
  int rest = (int)(idx / (KP / 4));
  int n = rest & 511;
  int g = rest >> 9;
  const float* src = nullptr; long o = 0;
  if (g == 0) {
    if (k4 < 256)       { src = Wix; o = (long)n * 256 + k4; }
    else if (k4 < 768)  { src = Wih; o = (long)n * 512 + (k4 - 256); }
    else if (k4 < 1280) { src = Wic; o = (long)n * 512 + (k4 - 768); }
  } else if (g == 1) {
    if (k4 < 256)       { src = Wfx; o = (long)n * 256 + k4; }
    else if (k4 < 768)  { src = Wfh; o = (long)n * 512 + (k4 - 256); }
    else if (k4 < 1280) { src = Wfc; o = (long)n * 512 + (k4 - 768); }
  } else if (g == 2) {
    if (k4 < 256)       { src = Wtx; o = (long)n * 256 + k4; }
  } else if (g == 3) {
    if (k4 < 256)       { src = Wcx; o = (long)n * 256 + k4; }
    else if (k4 < 768)  { src = Wch; o = (long)n * 512 + (k4 - 256); }
  } else if (g == 4) {
    if (k4 < 256)       { src = Wox; o = (long)n * 256 + k4; }
    else if (k4 < 768)  { src = Woh; o = (long)n * 512 + (k4 - 256); }
    else if (k4 < 1280) { src = Woc; o = (long)n * 512 + (k4 - 768); }
    else if (k4 < 1296) { src = Wot; o = (long)n * 16 + (k4 - 1280); }
  } else {
    if (k4 >= 1280 && k4 < 1296) { src = Wtt; o = (long)n * 16 + (k4 - 1280); }
  }
  float4 v = make_float4(0.f, 0.f, 0.f, 0.f);
  if (src) v = *(const float4*)(src + o);
  ushort4 u;
  u.x = f2bf(v.x); u.y = f2bf(v.y); u.z = f2bf(v.z); u.w = f2bf(v.w);
  *(ushort4*)(Wp + idx * 4) = u;
}

// LDS layout per slot (K-phase = 32 elems = 64 B per row):
//   A: byte = row*64 + ((kgrp + (row>>1))&3)*16,  row in [0,128)
//   W: byte = 8192 + RG[g]*8192 + col*64 + ((kgrp+(col>>1))&3)*16
// gld16 writes 1KB chunks (16 rows) linearly; per-lane source granule is
// pre-permuted (kslot) so the stored layout matches (linear-dest rule, r4-verified).

struct FragSet {
  bf16x8 a[4];
  bf16x8 b0[6];
  bf16x8 b1[6];
};

// stage half-tile ht into slot at byte base sb; 1+popcount(SMASK) loads per wave
template<unsigned SMASK>
__device__ __forceinline__ void stage(char* lds, int sb, int ht,
                                      const char* sA, const char* sW, int wid) {
  const unsigned kb = (unsigned)ht * 64u;
  gld16(sA + kb, lds + sb + wid * 1024);
#pragma unroll
  for (int g = 0; g < 6; ++g)
    if (SMASK & (1u << g))
      gld16(sW + (unsigned)g * GSTR + kb, lds + sb + 8192 + RG[g] * 8192 + wid * 1024);
}

template<unsigned MM>
__device__ __forceinline__ void mfma_cluster(const FragSet& f, f32x4 acc[6][4][2]) {
  __builtin_amdgcn_s_setprio(1);
#pragma unroll
  for (int g = 0; g < 6; ++g) {
    if (MM & (1u << g)) {
      acc[g][0][0] = __builtin_amdgcn_mfma_f32_16x16x32_bf16(f.a[0], f.b0[g], acc[g][0][0], 0, 0, 0);
      acc[g][1][0] = __builtin_amdgcn_mfma_f32_16x16x32_bf16(f.a[1], f.b0[g], acc[g][1][0], 0, 0, 0);
      acc[g][2][0] = __builtin_amdgcn_mfma_f32_16x16x32_bf16(f.a[2], f.b0[g], acc[g][2][0], 0, 0, 0);
      acc[g][3][0] = __builtin_amdgcn_mfma_f32_16x16x32_bf16(f.a[3], f.b0[g], acc[g][3][0], 0, 0, 0);
      acc[g][0][1] = __builtin_amdgcn_mfma_f32_16x16x32_bf16(f.a[0], f.b1[g], acc[g][0][1], 0, 0, 0);
      acc[g][1][1] = __builtin_amdgcn_mfma_f32_16x16x32_bf16(f.a[1], f.b1[g], acc[g][1][1], 0, 0, 0);
      acc[g][2][1] = __builtin_amdgcn_mfma_f32_16x16x32_bf16(f.a[2], f.b1[g], acc[g][2][1], 0, 0, 0);
      acc[g][3][1] = __builtin_amdgcn_mfma_f32_16x16x32_bf16(f.a[3], f.b1[g], acc[g][3][1], 0, 0, 0);
    }
  }
  __builtin_amdgcn_s_setprio(0);
}

// cross-phase pipelined phase:
//   lgkmcnt(0): reads(h-1) drained (issued a full phase ago -> free) AND makes
//     ring-3 reuse race-free: all waves drain slot-(h-1) reads before the barrier,
//     so stage(h+2) [slot (h-1)%3] issued after the barrier cannot race them.
//   vmcnt(NW): stage(h) landed (own chunks); barrier makes it CU-wide.
//   Then: issue reads(h)->cur, issue stage(h+2), and run the PURE MFMA cluster
//   on prev (filled last phase) with NO waitcnt -- reads/stage drain underneath.
template<unsigned RM, unsigned MM, unsigned SM, int NW, bool ST, bool MF>
__device__ __forceinline__ void phase(char* lds, int rs, int ws, int ht,
    const char* sA, const char* sW, int wid, int aro, int wro,
    FragSet& cur, const FragSet& prev, f32x4 acc[6][4][2]) {
  asm volatile("s_waitcnt vmcnt(%0) lgkmcnt(0)" :: "i"(NW) : "memory");
  __builtin_amdgcn_s_barrier();
  __builtin_amdgcn_sched_barrier(0);
  const char* base = lds + rs;
  // issue reads for phase h (consumed next phase)
  cur.a[0] = *(const bf16x8*)(base + aro);
  cur.a[1] = *(const bf16x8*)(base + aro + 1024);
  cur.a[2] = *(const bf16x8*)(base + aro + 2048);
  cur.a[3] = *(const bf16x8*)(base + aro + 3072);
#pragma unroll
  for (int g = 0; g < 6; ++g) {
    if (RM & (1u << g)) {
      cur.b0[g] = *(const bf16x8*)(base + 8192 + RG[g] * 8192 + wro);
      cur.b1[g] = *(const bf16x8*)(base + 8192 + RG[g] * 8192 + wro + 1024);
    }
  }
  if (ST) stage<SM>(lds, ws, ht, sA, sW, wid);   // issue-only; rides vmcnt
  __builtin_amdgcn_sched_barrier(0);             // pin reads/stage above the MFMAs
  if (MF) mfma_cluster<MM>(prev, acc);           // pure: no waitcnt before it
}

// ---------------- main fused kernel ----------------
__global__ __launch_bounds__(512, 2) void lstm_main(
    const unsigned short* __restrict__ Ap, const unsigned short* __restrict__ Wp,
    const float* __restrict__ c_prev,
    const float* __restrict__ b_ix, const float* __restrict__ b_fx,
    const float* __restrict__ b_tx, const float* __restrict__ b_cx,
    const float* __restrict__ b_ox,
    float* __restrict__ out)
{
  __shared__ __align__(16) char lds[3 * SLOT];   // 147456 B, 1 wg/CU

  const int tid  = threadIdx.x;
  const int lane = tid & 63;
  const int wid  = tid >> 6;

  // XCD swizzle: XCD pair {2c,2c+1} owns col-block c (W slice ~2MB, L2-resident)
  const int bid = blockIdx.x;
  const int xcd = bid & 7;
  const int idx = bid >> 3;                  // 0..63
  const int cb  = xcd >> 1;                  // 0..3
  const int rb  = (idx << 1) | (xcd & 1);    // 0..127
  const unsigned brow = (unsigned)rb * 128u;
  const int bcol = cb * 128;

  const int wr  = (wid >> 2) * 64;           // wave rows [wr, wr+64)
  const int wcg = (wid & 3) * 32;            // wave cols [wcg, wcg+32)
  const int lrow = lane & 15;
  const int kgrp = lane >> 4;

  f32x4 acc[6][4][2];
  {
    f32x4 z = {0.f, 0.f, 0.f, 0.f};
#pragma unroll
    for (int g = 0; g < 6; ++g)
#pragma unroll
      for (int i = 0; i < 4; ++i) { acc[g][i][0] = z; acc[g][i][1] = z; }
  }

  // swizzled read offsets
  const int sread = ((kgrp + (lrow >> 1)) & 3) << 4;
  const int aro = (wr + lrow) * 64 + sread;
  const int wro = (wcg + lrow) * 64 + sread;   // region-relative

  // stage source pointers (per-lane pre-permuted granule; r4-verified math)
  const int l4 = lane >> 2;
  const int kslot = (((lane & 3) - ((lane >> 3) & 3)) & 3) << 4;
  const char* sA = (const char*)Ap + (size_t)(brow + wid * 16 + l4) * KPB + kslot;
  const char* sW = (const char*)Wp + (size_t)(bcol + wid * 16 + l4) * KPB + kslot;

  FragSet fE, fO;

  // prologue: half-tiles 0,1 in flight
  stage<0x1F>(lds, 0,    0, sA, sW, wid);
  stage<0x1F>(lds, SLOT, 1, sA, sW, wid);

  int rs = 0;
#define PH(RMv, MMv, SMv, NWv, STv, MFv, HT, CUR, PRV) do {                    \
    int ws = (rs >= SLOT) ? rs - SLOT : rs + 2 * SLOT;                         \
    phase<RMv, MMv, SMv, NWv, STv, MFv>(lds, rs, ws, HT, sA, sW, wid,          \
                                        aro, wro, CUR, PRV, acc);              \
    rs = (rs == 2 * SLOT) ? 0 : rs + SLOT;                                     \
  } while (0)

  PH(0x1F, 0x00, 0x1F, 6, true, false, 2, fE, fO);         // h0
  PH(0x1F, 0x1F, 0x1F, 6, true, true,  3, fO, fE);         // h1
#pragma unroll 1
  for (int h = 2; h < 6; h += 2) {                          // h2..h5
    PH(0x1F, 0x1F, 0x1F, 6, true, true, h + 2, fE, fO);
    PH(0x1F, 0x1F, 0x1F, 6, true, true, h + 3, fO, fE);
  }
  PH(0x1F, 0x1F, 0x1B, 6, true, true,  8, fE, fO);         // h6
  PH(0x1F, 0x1F, 0x1B, 5, true, true,  9, fO, fE);         // h7
  PH(0x1B, 0x1F, 0x1B, 5, true, true, 10, fE, fO);         // h8
  PH(0x1B, 0x1B, 0x1B, 5, true, true, 11, fO, fE);         // h9
#pragma unroll 1
  for (int h = 10; h < 22; h += 2) {                        // h10..h21
    PH(0x1B, 0x1B, 0x1B, 5, true, true, h + 2, fE, fO);
    PH(0x1B, 0x1B, 0x1B, 5, true, true, h + 3, fO, fE);
  }
  PH(0x1B, 0x1B, 0x13, 5, true, true, 24, fE, fO);         // h22
  PH(0x1B, 0x1B, 0x13, 4, true, true, 25, fO, fE);         // h23
  PH(0x13, 0x1B, 0x13, 4, true, true, 26, fE, fO);         // h24
  PH(0x13, 0x13, 0x13, 4, true, true, 27, fO, fE);         // h25
#pragma unroll 1
  for (int h = 26; h < 38; h += 2) {                        // h26..h37
    PH(0x13, 0x13, 0x13, 4, true, true, h + 2, fE, fO);
    PH(0x13, 0x13, 0x13, 4, true, true, h + 3, fO, fE);
  }
  PH(0x13, 0x13, 0x30, 4, true,  true, 40, fE, fO);        // h38
  PH(0x13, 0x13, 0x00, 3, false, true,  0, fO, fE);        // h39
  PH(0x30, 0x13, 0x00, 0, false, true,  0, fE, fO);        // h40
#undef PH
  // flush: MFMA for h40's reads
  asm volatile("s_waitcnt lgkmcnt(0)" ::: "memory");
  __builtin_amdgcn_sched_barrier(0);
  mfma_cluster<0x30>(fE, acc);

  // ---------------- fused epilogue ----------------
  const int n0 = bcol + wcg + lrow;
  const int rbase = kgrp * 4;
#pragma unroll
  for (int cf = 0; cf < 2; ++cf) {
    const int n = n0 + 16 * cf;
    const float bi  = b_ix[n], bff = b_fx[n], bt = b_tx[n], bc = b_cx[n], bo = b_ox[n];
#pragma unroll
    for (int i = 0; i < 4; ++i) {
#pragma unroll
      for (int r = 0; r < 4; ++r) {
        const long m   = (long)brow + wr + 16 * i + rbase + r;
        const long off = m * H_SZ + n;
        const float iv = sigm(acc[0][i][cf][r] + bi);
        const float fv = sigm(acc[1][i][cf][r] + bff);
        const float Tv = sigm(acc[2][i][cf][r] + bt + sigm(acc[5][i][cf][r]));
        const float kv = tanhx(acc[3][i][cf][r] + bc);
        const float ov = sigm(acc[4][i][cf][r] + bo);
        const float cp = c_prev[off];
        const float cn = iv * Tv * kv + fv * cp;
        out[off]          = ov * tanhx(cn);
        out[BH + off]     = cn;
        out[2 * BH + off] = Tv;
      }
    }
  }
}

extern "C" void kernel_launch(void* const* d_in, const int* in_sizes, int n_in,
                              void* d_out, int out_size, void* d_ws, size_t ws_size,
                              hipStream_t stream) {
  const float* x      = (const float*)d_in[0];
  const float* h      = (const float*)d_in[1];
  const float* c_prev = (const float*)d_in[2];
  const float* dl     = (const float*)d_in[3];
  const float* W_ix = (const float*)d_in[4];
  const float* b_ix = (const float*)d_in[5];
  const float* W_ih = (const float*)d_in[6];
  const float* W_ic = (const float*)d_in[7];
  const float* W_fx = (const float*)d_in[8];
  const float* b_fx = (const float*)d_in[9];
  const float* W_fh = (const float*)d_in[10];
  const float* W_fc = (const float*)d_in[11];
  const float* W_tx = (const float*)d_in[12];
  const float* b_tx = (const float*)d_in[13];
  const float* W_tt = (const float*)d_in[14];
  const float* W_cx = (const float*)d_in[15];
  const float* b_cx = (const float*)d_in[16];
  const float* W_ch = (const float*)d_in[17];
  const float* W_ox = (const float*)d_in[18];
  const float* b_ox = (const float*)d_in[19];
  const float* W_oh = (const float*)d_in[20];
  const float* W_oc = (const float*)d_in[21];
  const float* W_ot = (const float*)d_in[22];

  unsigned short* Ap = (unsigned short*)d_ws;                                   // 44.04 MB
  unsigned short* Wp = (unsigned short*)((char*)d_ws + (size_t)B_SZ * KP * 2);  // +8.26 MB

  const long na4 = (long)B_SZ * KP / 4;
  prep_a_kernel<<<(int)((na4 + 255) / 256), 256, 0, stream>>>(x, h, c_prev, dl, Ap);
  const long nw4 = 6L * H_SZ * KP / 4;
  prep_w_kernel<<<(int)((nw4 + 255) / 256), 256, 0, stream>>>(
      W_ix, W_ih, W_ic, W_fx, W_fh, W_fc, W_tx, W_tt, W_cx, W_ch,
      W_ox, W_oh, W_oc, W_ot, Wp);

  lstm_main<<<512, 512, 0, stream>>>(Ap, Wp, c_prev, b_ix, b_fx, b_tx, b_cx, b_ox,
                                     (float*)d_out);
}

// Round 10
// 157.523 us; speedup vs baseline: 1.6055x; 1.6055x over previous
//
#include <hip/hip_runtime.h>
#include <cstdint>

#define B_SZ   16384
#define H_SZ   512
#define DIN    256
#define TEMB   16
#define KP     1344          // packed K: x[0,256) h[256,768) c[768,1280) delt[1280,1296) pad[1296,1344)
#define KPB    2688          // KP*2 bytes per row
#define BH     8388608L      // B_SZ*H_SZ
#define SLOT   36864         // LDS slot: A 16 KB (256 rows x 64 B) + 5 W regions x 4 KB
#define GSTR   1376256       // 512*KPB: gate stride in Wp bytes

typedef __attribute__((ext_vector_type(4))) float f32x4;
typedef __bf16 bf16x8 __attribute__((ext_vector_type(8)));

typedef const __attribute__((address_space(1))) unsigned int gu32_t;
typedef __attribute__((address_space(3)))       unsigned int lu32_t;

// gate -> W region (t and tt share region 4: never co-active)
__device__ constexpr int RG[6] = {0, 1, 4, 3, 2, 4};

__device__ __forceinline__ void gld16(const void* g, void* l) {
  __builtin_amdgcn_global_load_lds((gu32_t*)(uintptr_t)g,
                                   (lu32_t*)(unsigned int)(uintptr_t)l, 16, 0, 0);
}

__device__ __forceinline__ unsigned short f2bf(float f) {
  unsigned int u = __float_as_uint(f);
  u += 0x7FFFu + ((u >> 16) & 1u);   // RNE; inputs finite
  return (unsigned short)(u >> 16);
}

__device__ __forceinline__ float sigm(float v)  { return 1.0f / (1.0f + __expf(-v)); }
__device__ __forceinline__ float tanhx(float v) { return 2.0f / (1.0f + __expf(-2.0f * v)) - 1.0f; }

// ---------------- prep: pack A = [x|h|c|delt|0] as bf16 [B][KP] ----------------
__global__ void prep_a_kernel(const float* __restrict__ x, const float* __restrict__ h,
                              const float* __restrict__ c, const float* __restrict__ dl,
                              unsigned short* __restrict__ Ap) {
  long idx = (long)blockIdx.x * 256 + threadIdx.x;
  const long n4 = (long)B_SZ * KP / 4;
  if (idx >= n4) return;
  int row = (int)(idx / (KP / 4));
  int k4  = (int)(idx % (KP / 4)) * 4;
  float4 v = make_float4(0.f, 0.f, 0.f, 0.f);
  if (k4 < 256)       v = *(const float4*)(x  + (long)row * DIN  + k4);
  else if (k4 < 768)  v = *(const float4*)(h  + (long)row * H_SZ + (k4 - 256));
  else if (k4 < 1280) v = *(const float4*)(c  + (long)row * H_SZ + (k4 - 768));
  else if (k4 < 1296) v = *(const float4*)(dl + (long)row * TEMB + (k4 - 1280));
  ushort4 o;
  o.x = f2bf(v.x); o.y = f2bf(v.y); o.z = f2bf(v.z); o.w = f2bf(v.w);
  *(ushort4*)(Ap + idx * 4) = o;
}

// ---------------- prep: pack Wp[6][512][KP] bf16 ----------------
__global__ void prep_w_kernel(const float* __restrict__ Wix, const float* __restrict__ Wih, const float* __restrict__ Wic,
                              const float* __restrict__ Wfx, const float* __restrict__ Wfh, const float* __restrict__ Wfc,
                              const float* __restrict__ Wtx, const float* __restrict__ Wtt,
                              const float* __restrict__ Wcx, const float* __restrict__ Wch,
                              const float* __restrict__ Wox, const float* __restrict__ Woh,
                              const float* __restrict__ Woc, const float* __restrict__ Wot,
                              unsigned short* __restrict__ Wp) {
  long idx = (long)blockIdx.x * 256 + threadIdx.x;
  const long n4 = 6L * H_SZ * KP / 4;
  if (idx >= n4) return;
  int k4   = (int)(idx % (KP / 4)) * 4;
  int rest = (int)(idx / (KP / 4));
  int n = rest & 511;
  int g = rest >> 9;
  const float* src = nullptr; long o = 0;
  if (g == 0) {
    if (k4 < 256)       { src = Wix; o = (long)n * 256 + k4; }
    else if (k4 < 768)  { src = Wih; o = (long)n * 512 + (k4 - 256); }
    else if (k4 < 1280) { src = Wic; o = (long)n * 512 + (k4 - 768); }
  } else if (g == 1) {
    if (k4 < 256)       { src = Wfx; o = (long)n * 256 + k4; }
    else if (k4 < 768)  { src = Wfh; o = (long)n * 512 + (k4 - 256); }
    else if (k4 < 1280) { src = Wfc; o = (long)n * 512 + (k4 - 768); }
  } else if (g == 2) {
    if (k4 < 256)       { src = Wtx; o = (long)n * 256 + k4; }
  } else if (g == 3) {
    if (k4 < 256)       { src = Wcx; o = (long)n * 256 + k4; }
    else if (k4 < 768)  { src = Wch; o = (long)n * 512 + (k4 - 256); }
  } else if (g == 4) {
    if (k4 < 256)       { src = Wox; o = (long)n * 256 + k4; }
    else if (k4 < 768)  { src = Woh; o = (long)n * 512 + (k4 - 256); }
    else if (k4 < 1280) { src = Woc; o = (long)n * 512 + (k4 - 768); }
    else if (k4 < 1296) { src = Wot; o = (long)n * 16 + (k4 - 1280); }
  } else {
    if (k4 >= 1280 && k4 < 1296) { src = Wtt; o = (long)n * 16 + (k4 - 1280); }
  }
  float4 v = make_float4(0.f, 0.f, 0.f, 0.f);
  if (src) v = *(const float4*)(src + o);
  ushort4 u;
  u.x = f2bf(v.x); u.y = f2bf(v.y); u.z = f2bf(v.z); u.w = f2bf(v.w);
  *(ushort4*)(Wp + idx * 4) = u;
}

// LDS layout per slot (K-phase = 32 elems = 64 B per row):
//   A: byte = row*64 + ((kgrp + (row>>1))&3)*16,  row in [0,256)
//   W: byte = 16384 + RG[g]*4096 + col*64 + ((kgrp+(col>>1))&3)*16,  col in [0,64)
// gld16 writes 1KB chunks (16 rows) linearly; per-lane source granule is
// pre-permuted (kslot) so the stored layout matches (linear-dest rule, r4-verified).

// stage half-tile ht into slot at base sb.
// A (16 chunks): wave w -> chunks {2w, 2w+1} = rows [32w, 32w+32).
// W (4 chunks per active gate): chunk (g,c) -> wave (4g+c)&7.
template<unsigned SMASK>
__device__ __forceinline__ void stage(char* lds, int sb, int ht,
                                      const char* sAb, const char* sWb, int wid) {
  const unsigned kb = (unsigned)ht * 64u;
  gld16(sAb + kb,            lds + sb + wid * 2048);
  gld16(sAb + kb + 16u * KPB, lds + sb + wid * 2048 + 1024);
#pragma unroll
  for (int g = 0; g < 6; ++g) {
    if (SMASK & (1u << g)) {
#pragma unroll
      for (int c = 0; c < 4; ++c) {
        if (((4 * g + c) & 7) == wid)   // wave-uniform scalar compare
          gld16(sWb + (unsigned)g * GSTR + (unsigned)c * (16u * KPB) + kb,
                lds + sb + 16384 + RG[g] * 4096 + c * 1024);
      }
    }
  }
}

template<unsigned CM>
__device__ __forceinline__ void comp(const char* lds, int sb, int aro, int wro,
                                     f32x4 acc[6][8]) {
  const char* base = lds + sb;
  bf16x8 a[8];
#pragma unroll
  for (int i = 0; i < 8; ++i)
    a[i] = *(const bf16x8*)(base + aro + i * 1024);
  __builtin_amdgcn_s_setprio(1);
#pragma unroll
  for (int g = 0; g < 6; ++g) {
    if (CM & (1u << g)) {
      bf16x8 b = *(const bf16x8*)(base + 16384 + RG[g] * 4096 + wro);
#pragma unroll
      for (int i = 0; i < 8; ++i)
        acc[g][i] = __builtin_amdgcn_mfma_f32_16x16x32_bf16(a[i], b, acc[g][i], 0, 0, 0);
    }
  }
  __builtin_amdgcn_s_setprio(0);
}

// classic double-buffer phase (r2-proven): stage(h+1) -> comp(h) -> syncthreads.
// The vmcnt/lgkm drain at the barrier is covered by the CO-RESIDENT second wg
// on the same CU (independent barrier, desynced phase rhythm).
template<unsigned CM, unsigned SM, bool ST>
__device__ __forceinline__ void phase(char* lds, int h, const char* sAb, const char* sWb,
                                      int wid, int aro, int wro, f32x4 acc[6][8]) {
  if (ST) stage<SM>(lds, ((h + 1) & 1) * SLOT, h + 1, sAb, sWb, wid);
  comp<CM>(lds, (h & 1) * SLOT, aro, wro, acc);
  __syncthreads();
}

// ---------------- main fused kernel ----------------
__global__ __launch_bounds__(512, 2) void lstm_main(
    const unsigned short* __restrict__ Ap, const unsigned short* __restrict__ Wp,
    const float* __restrict__ c_prev,
    const float* __restrict__ b_ix, const float* __restrict__ b_fx,
    const float* __restrict__ b_tx, const float* __restrict__ b_cx,
    const float* __restrict__ b_ox,
    float* __restrict__ out)
{
  __shared__ __align__(16) char lds[2 * SLOT];   // 73728 B -> 2 wgs/CU co-resident

  const int tid  = threadIdx.x;
  const int lane = tid & 63;
  const int wid  = tid >> 6;

  // XCD swizzle: XCD k owns col-block k (W slice ~1 MB, L2-resident); 512 wgs = 2/CU
  const int bid = blockIdx.x;
  const int cb  = bid & 7;                   // 0..7
  const int rb  = bid >> 3;                  // 0..63
  const unsigned brow = (unsigned)rb * 256u;
  const int bcol = cb * 64;

  const int wr  = (wid >> 2) * 128;          // wave rows [wr, wr+128)
  const int wcg = (wid & 3) * 16;            // wave cols [wcg, wcg+16)
  const int lrow = lane & 15;
  const int kgrp = lane >> 4;

  f32x4 acc[6][8];
  {
    f32x4 z = {0.f, 0.f, 0.f, 0.f};
#pragma unroll
    for (int g = 0; g < 6; ++g)
#pragma unroll
      for (int i = 0; i < 8; ++i) acc[g][i] = z;
  }

  // swizzled read offsets
  const int sread = ((kgrp + (lrow >> 1)) & 3) << 4;
  const int aro = (wr + lrow) * 64 + sread;
  const int wro = (wcg + lrow) * 64 + sread;   // region-relative

  // stage source pointers (per-lane pre-permuted granule; r4-verified math)
  const int l4 = lane >> 2;
  const int kslot = (((lane & 3) - ((lane >> 3) & 3)) & 3) << 4;
  const char* sAb = (const char*)Ap + (size_t)(brow + wid * 32 + l4) * KPB + kslot;
  const char* sWb = (const char*)Wp + (size_t)(bcol + l4) * KPB + kslot;

  // prologue
  stage<0x1F>(lds, 0, 0, sAb, sWb, wid);
  __syncthreads();

#pragma unroll 1
  for (int h = 0; h < 7; ++h)
    phase<0x1F, 0x1F, true>(lds, h, sAb, sWb, wid, aro, wro, acc);
  phase<0x1F, 0x1B, true>(lds, 7, sAb, sWb, wid, aro, wro, acc);
#pragma unroll 1
  for (int h = 8; h < 23; ++h)
    phase<0x1B, 0x1B, true>(lds, h, sAb, sWb, wid, aro, wro, acc);
  phase<0x1B, 0x13, true>(lds, 23, sAb, sWb, wid, aro, wro, acc);
#pragma unroll 1
  for (int h = 24; h < 39; ++h)
    phase<0x13, 0x13, true>(lds, h, sAb, sWb, wid, aro, wro, acc);
  phase<0x13, 0x30, true>(lds, 39, sAb, sWb, wid, aro, wro, acc);
  comp<0x30>(lds, (40 & 1) * SLOT, aro, wro, acc);

  // ---------------- fused epilogue ----------------
  const int n = bcol + wcg + lrow;
  const float bi  = b_ix[n], bff = b_fx[n], bt = b_tx[n], bc = b_cx[n], bo = b_ox[n];
  const int rbase = kgrp * 4;
#pragma unroll
  for (int i = 0; i < 8; ++i) {
#pragma unroll
    for (int r = 0; r < 4; ++r) {
      const long m   = (long)brow + wr + 16 * i + rbase + r;
      const long off = m * H_SZ + n;
      const float iv = sigm(acc[0][i][r] + bi);
      const float fv = sigm(acc[1][i][r] + bff);
      const float Tv = sigm(acc[2][i][r] + bt + sigm(acc[5][i][r]));
      const float kv = tanhx(acc[3][i][r] + bc);
      const float ov = sigm(acc[4][i][r] + bo);
      const float cp = c_prev[off];
      const float cn = iv * Tv * kv + fv * cp;
      out[off]          = ov * tanhx(cn);
      out[BH + off]     = cn;
      out[2 * BH + off] = Tv;
    }
  }
}

extern "C" void kernel_launch(void* const* d_in, const int* in_sizes, int n_in,
                              void* d_out, int out_size, void* d_ws, size_t ws_size,
                              hipStream_t stream) {
  const float* x      = (const float*)d_in[0];
  const float* h      = (const float*)d_in[1];
  const float* c_prev = (const float*)d_in[2];
  const float* dl     = (const float*)d_in[3];
  const float* W_ix = (const float*)d_in[4];
  const float* b_ix = (const float*)d_in[5];
  const float* W_ih = (const float*)d_in[6];
  const float* W_ic = (const float*)d_in[7];
  const float* W_fx = (const float*)d_in[8];
  const float* b_fx = (const float*)d_in[9];
  const float* W_fh = (const float*)d_in[10];
  const float* W_fc = (const float*)d_in[11];
  const float* W_tx = (const float*)d_in[12];
  const float* b_tx = (const float*)d_in[13];
  const float* W_tt = (const float*)d_in[14];
  const float* W_cx = (const float*)d_in[15];
  const float* b_cx = (const float*)d_in[16];
  const float* W_ch = (const float*)d_in[17];
  const float* W_ox = (const float*)d_in[18];
  const float* b_ox = (const float*)d_in[19];
  const float* W_oh = (const float*)d_in[20];
  const float* W_oc = (const float*)d_in[21];
  const float* W_ot = (const float*)d_in[22];

  unsigned short* Ap = (unsigned short*)d_ws;                                   // 44.04 MB
  unsigned short* Wp = (unsigned short*)((char*)d_ws + (size_t)B_SZ * KP * 2);  // +8.26 MB

  const long na4 = (long)B_SZ * KP / 4;
  prep_a_kernel<<<(int)((na4 + 255) / 256), 256, 0, stream>>>(x, h, c_prev, dl, Ap);
  const long nw4 = 6L * H_SZ * KP / 4;
  prep_w_kernel<<<(int)((nw4 + 255) / 256), 256, 0, stream>>>(
      W_ix, W_ih, W_ic, W_fx, W_fh, W_fc, W_tx, W_tt, W_cx, W_ch,
      W_ox, W_oh, W_oc, W_ot, Wp);

  lstm_main<<<512, 512, 0, stream>>>(Ap, Wp, c_prev, b_ix, b_fx, b_tx, b_cx, b_ox,
                                     (float*)d_out);
}

// Round 11
// 145.421 us; speedup vs baseline: 1.7391x; 1.0832x over previous
//
#include <hip/hip_runtime.h>
#include <cstdint>

#define B_SZ   16384
#define H_SZ   512
#define DIN    256
#define TEMB   16
#define KP     1344          // packed K: x[0,256) h[256,768) c[768,1280) delt[1280,1296) pad[1296,1344)
#define KPB    2688          // KP*2 bytes per row
#define BH     8388608L      // B_SZ*H_SZ
#define SLOT   26624         // LDS slot: A 16 KB (256 rows x 64 B) + 5 W regions x 2 KB (32 cols)
#define GSTR   1376256       // 512*KPB: gate stride in Wp bytes

typedef __attribute__((ext_vector_type(4))) float f32x4;
typedef __bf16 bf16x8 __attribute__((ext_vector_type(8)));

typedef const __attribute__((address_space(1))) unsigned int gu32_t;
typedef __attribute__((address_space(3)))       unsigned int lu32_t;

// gate -> W region (t and tt share region 4: never co-active)
__device__ constexpr int RG[6] = {0, 1, 4, 3, 2, 4};

__device__ __forceinline__ void gld16(const void* g, void* l) {
  __builtin_amdgcn_global_load_lds((gu32_t*)(uintptr_t)g,
                                   (lu32_t*)(unsigned int)(uintptr_t)l, 16, 0, 0);
}

__device__ __forceinline__ unsigned short f2bf(float f) {
  unsigned int u = __float_as_uint(f);
  u += 0x7FFFu + ((u >> 16) & 1u);   // RNE; inputs finite
  return (unsigned short)(u >> 16);
}

__device__ __forceinline__ float sigm(float v)  { return 1.0f / (1.0f + __expf(-v)); }
__device__ __forceinline__ float tanhx(float v) { return 2.0f / (1.0f + __expf(-2.0f * v)) - 1.0f; }

// ---------------- prep: pack A = [x|h|c|delt|0] as bf16 [B][KP] ----------------
__global__ void prep_a_kernel(const float* __restrict__ x, const float* __restrict__ h,
                              const float* __restrict__ c, const float* __restrict__ dl,
                              unsigned short* __restrict__ Ap) {
  long idx = (long)blockIdx.x * 256 + threadIdx.x;
  const long n4 = (long)B_SZ * KP / 4;
  if (idx >= n4) return;
  int row = (int)(idx / (KP / 4));
  int k4  = (int)(idx % (KP / 4)) * 4;
  float4 v = make_float4(0.f, 0.f, 0.f, 0.f);
  if (k4 < 256)       v = *(const float4*)(x  + (long)row * DIN  + k4);
  else if (k4 < 768)  v = *(const float4*)(h  + (long)row * H_SZ + (k4 - 256));
  else if (k4 < 1280) v = *(const float4*)(c  + (long)row * H_SZ + (k4 - 768));
  else if (k4 < 1296) v = *(const float4*)(dl + (long)row * TEMB + (k4 - 1280));
  ushort4 o;
  o.x = f2bf(v.x); o.y = f2bf(v.y); o.z = f2bf(v.z); o.w = f2bf(v.w);
  *(ushort4*)(Ap + idx * 4) = o;
}

// ---------------- prep: pack Wp[6][512][KP] bf16 ----------------
__global__ void prep_w_kernel(const float* __restrict__ Wix, const float* __restrict__ Wih, const float* __restrict__ Wic,
                              const float* __restrict__ Wfx, const float* __restrict__ Wfh, const float* __restrict__ Wfc,
                              const float* __restrict__ Wtx, const float* __restrict__ Wtt,
                              const float* __restrict__ Wcx, const float* __restrict__ Wch,
                              const float* __restrict__ Wox, const float* __restrict__ Woh,
                              const float* __restrict__ Woc, const float* __restrict__ Wot,
                              unsigned short* __restrict__ Wp) {
  long idx = (long)blockIdx.x * 256 + threadIdx.x;
  const long n4 = 6L * H_SZ * KP / 4;
  if (idx >= n4) return;
  int k4   = (int)(idx % (KP / 4)) * 4;
  int rest = (int)(idx / (KP / 4));
  int n = rest & 511;
  int g = rest >> 9;
  const float* src = nullptr; long o = 0;
  if (g == 0) {
    if (k4 < 256)       { src = Wix; o = (long)n * 256 + k4; }
    else if (k4 < 768)  { src = Wih; o = (long)n * 512 + (k4 - 256); }
    else if (k4 < 1280) { src = Wic; o = (long)n * 512 + (k4 - 768); }
  } else if (g == 1) {
    if (k4 < 256)       { src = Wfx; o = (long)n * 256 + k4; }
    else if (k4 < 768)  { src = Wfh; o = (long)n * 512 + (k4 - 256); }
    else if (k4 < 1280) { src = Wfc; o = (long)n * 512 + (k4 - 768); }
  } else if (g == 2) {
    if (k4 < 256)       { src = Wtx; o = (long)n * 256 + k4; }
  } else if (g == 3) {
    if (k4 < 256)       { src = Wcx; o = (long)n * 256 + k4; }
    else if (k4 < 768)  { src = Wch; o = (long)n * 512 + (k4 - 256); }
  } else if (g == 4) {
    if (k4 < 256)       { src = Wox; o = (long)n * 256 + k4; }
    else if (k4 < 768)  { src = Woh; o = (long)n * 512 + (k4 - 256); }
    else if (k4 < 1280) { src = Woc; o = (long)n * 512 + (k4 - 768); }
    else if (k4 < 1296) { src = Wot; o = (long)n * 16 + (k4 - 1280); }
  } else {
    if (k4 >= 1280 && k4 < 1296) { src = Wtt; o = (long)n * 16 + (k4 - 1280); }
  }
  float4 v = make_float4(0.f, 0.f, 0.f, 0.f);
  if (src) v = *(const float4*)(src + o);
  ushort4 u;
  u.x = f2bf(v.x); u.y = f2bf(v.y); u.z = f2bf(v.z); u.w = f2bf(v.w);
  *(ushort4*)(Wp + idx * 4) = u;
}

// LDS layout per slot (K-phase = 32 elems = 64 B per row):
//   A: byte = row*64 + ((kgrp + (lrow>>1))&3)*16,  row in [0,256)
//   W: byte = 16384 + RG[g]*2048 + col*64 + swz,   col in [0,32)
// gld16 writes 1KB chunks (16 rows) linearly; per-lane source granule is
// pre-permuted (kslot) so the stored layout matches (linear-dest rule, r4-verified).

// stage half-tile ht into slot at base sb.
// A (16 chunks): wave w -> chunks {2w,2w+1} = rows [32w, 32w+32).
// W (2 chunks per active gate): chunk (g,c) -> wave (2g+c)&7.
template<unsigned SMASK>
__device__ __forceinline__ void stage(char* lds, int sb, int ht,
                                      const char* sAb, const char* sWb, int wid) {
  const unsigned kb = (unsigned)ht * 64u;
  gld16(sAb + kb,              lds + sb + wid * 2048);
  gld16(sAb + kb + 16u * KPB,  lds + sb + wid * 2048 + 1024);
#pragma unroll
  for (int g = 0; g < 6; ++g) {
    if (SMASK & (1u << g)) {
#pragma unroll
      for (int c = 0; c < 2; ++c) {
        if (((2 * g + c) & 7) == wid)   // wave-uniform scalar compare
          gld16(sWb + (unsigned)g * GSTR + (unsigned)c * (16u * KPB) + kb,
                lds + sb + 16384 + RG[g] * 2048 + c * 1024);
      }
    }
  }
}

template<unsigned CM>
__device__ __forceinline__ void comp(const char* lds, int sb, int aro, int wro,
                                     f32x4 acc[6][4]) {
  const char* base = lds + sb;
  bf16x8 a[4];
#pragma unroll
  for (int i = 0; i < 4; ++i)
    a[i] = *(const bf16x8*)(base + aro + i * 1024);
  __builtin_amdgcn_s_setprio(1);
#pragma unroll
  for (int g = 0; g < 6; ++g) {
    if (CM & (1u << g)) {
      bf16x8 b = *(const bf16x8*)(base + 16384 + RG[g] * 2048 + wro);
#pragma unroll
      for (int i = 0; i < 4; ++i)
        acc[g][i] = __builtin_amdgcn_mfma_f32_16x16x32_bf16(a[i], b, acc[g][i], 0, 0, 0);
    }
  }
  __builtin_amdgcn_s_setprio(0);
}

// classic double-buffer phase: stage(h+1) -> comp(h) -> syncthreads.
// Drain at the barrier is covered by the co-resident wg + 4 waves/SIMD TLP.
template<unsigned CM, unsigned SM, bool ST>
__device__ __forceinline__ void phase(char* lds, int h, const char* sAb, const char* sWb,
                                      int wid, int aro, int wro, f32x4 acc[6][4]) {
  if (ST) stage<SM>(lds, ((h + 1) & 1) * SLOT, h + 1, sAb, sWb, wid);
  comp<CM>(lds, (h & 1) * SLOT, aro, wro, acc);
  __syncthreads();
}

// ---------------- main fused kernel ----------------
__global__ __launch_bounds__(512, 4) void lstm_main(
    const unsigned short* __restrict__ Ap, const unsigned short* __restrict__ Wp,
    const float* __restrict__ c_prev,
    const float* __restrict__ b_ix, const float* __restrict__ b_fx,
    const float* __restrict__ b_tx, const float* __restrict__ b_cx,
    const float* __restrict__ b_ox,
    float* __restrict__ out)
{
  __shared__ __align__(16) char lds[2 * SLOT];   // 53248 B -> 2 wgs/CU LDS-wise

  const int tid  = threadIdx.x;
  const int lane = tid & 63;
  const int wid  = tid >> 6;

  // XCD swizzle: XCD k owns col-blocks {2k,2k+1} (W slice ~1 MB, L2-resident)
  const int bid = blockIdx.x;
  const int xcd = bid & 7;
  const int idx = bid >> 3;                  // 0..127
  const int cb  = (xcd << 1) | (idx & 1);    // 0..15
  const int rb  = idx >> 1;                  // 0..63
  const unsigned brow = (unsigned)rb * 256u;
  const int bcol = cb * 32;

  const int wr  = (wid >> 1) * 64;           // wave rows [wr, wr+64)
  const int wcg = (wid & 1) * 16;            // wave cols [wcg, wcg+16)
  const int lrow = lane & 15;
  const int kgrp = lane >> 4;

  f32x4 acc[6][4];
  {
    f32x4 z = {0.f, 0.f, 0.f, 0.f};
#pragma unroll
    for (int g = 0; g < 6; ++g)
#pragma unroll
      for (int i = 0; i < 4; ++i) acc[g][i] = z;
  }

  // swizzled read offsets
  const int sread = ((kgrp + (lrow >> 1)) & 3) << 4;
  const int aro = (wr + lrow) * 64 + sread;
  const int wro = (wcg + lrow) * 64 + sread;   // region-relative

  // stage source pointers (per-lane pre-permuted granule; r4-verified math)
  const int l4 = lane >> 2;
  const int kslot = (((lane & 3) - ((lane >> 3) & 3)) & 3) << 4;
  const char* sAb = (const char*)Ap + (size_t)(brow + wid * 32 + l4) * KPB + kslot;
  const char* sWb = (const char*)Wp + (size_t)(bcol + l4) * KPB + kslot;

  // prologue
  stage<0x1F>(lds, 0, 0, sAb, sWb, wid);
  __syncthreads();

#pragma unroll 1
  for (int h = 0; h < 7; ++h)
    phase<0x1F, 0x1F, true>(lds, h, sAb, sWb, wid, aro, wro, acc);
  phase<0x1F, 0x1B, true>(lds, 7, sAb, sWb, wid, aro, wro, acc);
#pragma unroll 1
  for (int h = 8; h < 23; ++h)
    phase<0x1B, 0x1B, true>(lds, h, sAb, sWb, wid, aro, wro, acc);
  phase<0x1B, 0x13, true>(lds, 23, sAb, sWb, wid, aro, wro, acc);
#pragma unroll 1
  for (int h = 24; h < 39; ++h)
    phase<0x13, 0x13, true>(lds, h, sAb, sWb, wid, aro, wro, acc);
  phase<0x13, 0x30, true>(lds, 39, sAb, sWb, wid, aro, wro, acc);
  comp<0x30>(lds, (40 & 1) * SLOT, aro, wro, acc);

  // ---------------- fused epilogue ----------------
  const int n = bcol + wcg + lrow;
  const float bi  = b_ix[n], bff = b_fx[n], bt = b_tx[n], bc = b_cx[n], bo = b_ox[n];
  const int rbase = kgrp * 4;
#pragma unroll
  for (int i = 0; i < 4; ++i) {
#pragma unroll
    for (int r = 0; r < 4; ++r) {
      const long m   = (long)brow + wr + 16 * i + rbase + r;
      const long off = m * H_SZ + n;
      const float iv = sigm(acc[0][i][r] + bi);
      const float fv = sigm(acc[1][i][r] + bff);
      const float Tv = sigm(acc[2][i][r] + bt + sigm(acc[5][i][r]));
      const float kv = tanhx(acc[3][i][r] + bc);
      const float ov = sigm(acc[4][i][r] + bo);
      const float cp = c_prev[off];
      const float cn = iv * Tv * kv + fv * cp;
      out[off]          = ov * tanhx(cn);
      out[BH + off]     = cn;
      out[2 * BH + off] = Tv;
    }
  }
}

extern "C" void kernel_launch(void* const* d_in, const int* in_sizes, int n_in,
                              void* d_out, int out_size, void* d_ws, size_t ws_size,
                              hipStream_t stream) {
  const float* x      = (const float*)d_in[0];
  const float* h      = (const float*)d_in[1];
  const float* c_prev = (const float*)d_in[2];
  const float* dl     = (const float*)d_in[3];
  const float* W_ix = (const float*)d_in[4];
  const float* b_ix = (const float*)d_in[5];
  const float* W_ih = (const float*)d_in[6];
  const float* W_ic = (const float*)d_in[7];
  const float* W_fx = (const float*)d_in[8];
  const float* b_fx = (const float*)d_in[9];
  const float* W_fh = (const float*)d_in[10];
  const float* W_fc = (const float*)d_in[11];
  const float* W_tx = (const float*)d_in[12];
  const float* b_tx = (const float*)d_in[13];
  const float* W_tt = (const float*)d_in[14];
  const float* W_cx = (const float*)d_in[15];
  const float* b_cx = (const float*)d_in[16];
  const float* W_ch = (const float*)d_in[17];
  const float* W_ox = (const float*)d_in[18];
  const float* b_ox = (const float*)d_in[19];
  const float* W_oh = (const float*)d_in[20];
  const float* W_oc = (const float*)d_in[21];
  const float* W_ot = (const float*)d_in[22];

  unsigned short* Ap = (unsigned short*)d_ws;                                   // 44.04 MB
  unsigned short* Wp = (unsigned short*)((char*)d_ws + (size_t)B_SZ * KP * 2);  // +8.26 MB

  const long na4 = (long)B_SZ * KP / 4;
  prep_a_kernel<<<(int)((na4 + 255) / 256), 256, 0, stream>>>(x, h, c_prev, dl, Ap);
  const long nw4 = 6L * H_SZ * KP / 4;
  prep_w_kernel<<<(int)((nw4 + 255) / 256), 256, 0, stream>>>(
      W_ix, W_ih, W_ic, W_fx, W_fh, W_fc, W_tx, W_tt, W_cx, W_ch,
      W_ox, W_oh, W_oc, W_ot, Wp);

  lstm_main<<<1024, 512, 0, stream>>>(Ap, Wp, c_prev, b_ix, b_fx, b_tx, b_cx, b_ox,
                                      (float*)d_out);
}